// Round 9
// baseline (854.881 us; speedup 1.0000x reference)
//
#include <hip/hip_runtime.h>

constexpr int IN_F  = 256;
constexpr int OUT_F = 512;
constexpr int BATCH = 2048;

// pack[(o,i)] = {p0,p1,p2,p3 | q1,q2,q3,w} : one aligned 32B record.
__global__ __launch_bounds__(256) void prep_pack8_kernel(
    const float* __restrict__ p, const float* __restrict__ q,
    const float* __restrict__ w, float4* __restrict__ pk, int n) {
    int t = blockIdx.x * 256 + threadIdx.x;
    if (t < n) {
        pk[2 * t]     = make_float4(p[4 * t], p[4 * t + 1], p[4 * t + 2], p[4 * t + 3]);
        pk[2 * t + 1] = make_float4(q[3 * t], q[3 * t + 1], q[3 * t + 2], w[t]);
    }
}

// x3[b,i] = RN(x^3) via f64, once per (b,i).
__global__ __launch_bounds__(256) void prep_x3_kernel(
    const float* __restrict__ x, float* __restrict__ x3, int n) {
    int t = blockIdx.x * 256 + threadIdx.x;
    if (t < n) {
        const double xd = (double)x[t];
        x3[t] = (float)(xd * xd * xd);   // RN(x^3) == powf(x,3)
    }
}

// Block = 64 batches (lanes) x 8 outputs; waves split the i-dimension; each
// wave computes all 8 outputs (x-powers amortized 8x).
//
// R9: coefficients delivered via per-lane BROADCAST global_load_dwordx4
// (wave-uniform address; 1 L1 transaction, result in VGPRs). The VMEM pipe
// pipelines deeply with counted vmcnt (unlike the shallow SMEM/s_load path
// that R4-R8 showed to be the stall source). threadIdx.y (runtime 0) is
// mixed into the index so the compiler cannot prove uniformity and
// re-scalarize the load. All operands in VGPRs -> no SGPR-port movs.
// R7's LDS staging (scratch spill) and R8's unroll-2 both regressed; do
// not revisit.
//
// NUMERICS (bit-exact vs np reference -- DO NOT REORDER, verified R3-R8,
// absmax 768 vs threshold 5.7e5):
//   x^2 = RN(x*x); x^3 = RN(x^3) via f64 table; S = fmaf chain ascending p
//   starting from RN(c1*x); Q' = (1+S)+1e-6 as two separate adds; division
//   via rcp (relative-error-only).
template <int MODE>   // 2 = packed + x3 table (VMEM broadcast); 1 = packed
                      // s_load; 0 = raw arrays
__global__ __launch_bounds__(256, 8) void kan_kernel(
    const float*  __restrict__ x,
    const float4* __restrict__ Pc,    // (O, I) of {p0,p1,p2,p3}
    const float*  __restrict__ Qc,    // (O, I, 3) raw (MODE 0)
    const float4* __restrict__ PK,    // (O, I) 2x float4 records (MODE >= 1)
    const float*  __restrict__ X3,    // (B, I) RN(x^3) table (MODE 2)
    const float*  __restrict__ W,     // (O, I) raw (MODE 0)
    const float*  __restrict__ bias,  // (O)
    float* __restrict__ out)          // (B, O)
{
#pragma clang fp contract(off)       // protect the explicit add sequence
    const int lane  = threadIdx.x & 63;
    const int wave  = __builtin_amdgcn_readfirstlane(threadIdx.x >> 6);
    const int b     = blockIdx.x * 64 + lane;
    const int o0    = blockIdx.y * 8;
    const int ibase = wave * 64;      // this wave's i-slice
    const int yoff  = threadIdx.y;    // runtime 0; defeats uniform-promotion

    float acc[8] = {0.f, 0.f, 0.f, 0.f, 0.f, 0.f, 0.f, 0.f};
    const float* xrow  = x + (size_t)b * IN_F + ibase;
    const float* x3row = (MODE == 2) ? (X3 + (size_t)b * IN_F + ibase) : nullptr;

    for (int ic = 0; ic < 64; ic += 4) {
        const float4 xq = *reinterpret_cast<const float4*>(xrow + ic);
        float x1[4] = {xq.x, xq.y, xq.z, xq.w};
        float x2[4], x3v[4];
        if (MODE == 2) {
            const float4 x3q = *reinterpret_cast<const float4*>(x3row + ic);
            x3v[0] = x3q.x; x3v[1] = x3q.y; x3v[2] = x3q.z; x3v[3] = x3q.w;
#pragma unroll
            for (int j = 0; j < 4; ++j) x2[j] = x1[j] * x1[j];  // RN(x^2)
        } else {
#pragma unroll
            for (int j = 0; j < 4; ++j) {
                x2[j] = x1[j] * x1[j];
                const double xd = (double)x1[j];
                x3v[j] = (float)(xd * xd * xd);
            }
        }
        const int rowi = ibase + ic;
#pragma unroll
        for (int oo = 0; oo < 8; ++oo) {
            const int rowbase = (o0 + oo) * IN_F + rowi;
#pragma unroll
            for (int j = 0; j < 4; ++j) {          // 4 contiguous 32B records
                float p0, p1, p2, p3, q1, q2, q3, wv;
                if (MODE == 2) {
                    // Broadcast VMEM load (uniform addr masked by yoff).
                    const float4* rec = PK + 2 * (size_t)(rowbase + j) + yoff;
                    const float4 pa = rec[0];
                    const float4 pb = rec[1];
                    p0 = pa.x; p1 = pa.y; p2 = pa.z; p3 = pa.w;
                    q1 = pb.x; q2 = pb.y; q3 = pb.z; wv = pb.w;
                } else if (MODE == 1) {
                    const float4 pa = PK[2 * (size_t)(rowbase + j)];
                    const float4 pb = PK[2 * (size_t)(rowbase + j) + 1];
                    p0 = pa.x; p1 = pa.y; p2 = pa.z; p3 = pa.w;
                    q1 = pb.x; q2 = pb.y; q3 = pb.z; wv = pb.w;
                } else {
                    const float4 pc = Pc[rowbase + j];
                    const float* qp = Qc + (size_t)(rowbase + j) * 3;
                    p0 = pc.x; p1 = pc.y; p2 = pc.z; p3 = pc.w;
                    q1 = qp[0]; q2 = qp[1]; q3 = qp[2];
                    wv = W[rowbase + j];
                }
                // ---- S_Q : einsum fmaf chain, accum starts at 0 ----
                float t = q1 * x1[j];              // == fma(q1,x1,0)
                t = fmaf(q2, x2[j], t);
                t = fmaf(q3, x3v[j], t);
                float Qv = 1.0f + t;               // Sterbenz-exact near pole
                float Qp = Qv + 1e-6f;
                // ---- S_P : same einsum chain ----
                float s = fmaf(p1, x1[j], p0);
                s = fmaf(p2, x2[j], s);
                s = fmaf(p3, x3v[j], s);
                const float r = __builtin_amdgcn_rcpf(Qp);
                acc[oo] = fmaf(s, r, acc[oo]);       // rational term
                acc[oo] = fmaf(wv, x1[j], acc[oo]);  // fused base matmul
            }
        }
    }

    // ---- cross-wave reduction: red[wave][lane][9] (pad -> conflict-free) ----
    __shared__ float red[4 * 64 * 9];
    {
        float* dst = &red[(wave * 64 + lane) * 9];
#pragma unroll
        for (int v = 0; v < 8; ++v) dst[v] = acc[v];
    }
    __syncthreads();

#pragma unroll
    for (int k = 0; k < 2; ++k) {
        const int idx = threadIdx.x + k * 256;     // idx = bb*8 + o
        const int bb = idx >> 3, o = idx & 7;
        const int e = bb * 9 + o;
        float s = red[e] + red[576 + e];           // wave order 0,1,2,3
        s = s + red[1152 + e];
        s = s + red[1728 + e];
        s = s + bias[o0 + o];
        out[(size_t)(blockIdx.x * 64 + bb) * OUT_F + o0 + o] = s;
    }
}

extern "C" void kernel_launch(void* const* d_in, const int* in_sizes, int n_in,
                              void* d_out, int out_size, void* d_ws, size_t ws_size,
                              hipStream_t stream) {
    const float* x    = (const float*)d_in[0];
    const float* Pc   = (const float*)d_in[1];
    const float* Qc   = (const float*)d_in[2];
    const float* W    = (const float*)d_in[3];
    const float* bias = (const float*)d_in[4];
    float* out = (float*)d_out;

    const int n  = OUT_F * IN_F;          // 131072 (o,i) records
    const int nx = BATCH * IN_F;          // 524288 (b,i) x-powers
    const size_t pk_bytes = (size_t)n * 32;
    dim3 grid(BATCH / 64, OUT_F / 8);     // 2048 blocks = 8/CU

    if (ws_size >= pk_bytes + (size_t)nx * sizeof(float)) {
        float4* pk = (float4*)d_ws;
        float*  x3 = (float*)((char*)d_ws + pk_bytes);
        prep_pack8_kernel<<<(n + 255) / 256, 256, 0, stream>>>(Pc, Qc, W, pk, n);
        prep_x3_kernel<<<(nx + 255) / 256, 256, 0, stream>>>(x, x3, nx);
        kan_kernel<2><<<grid, 256, 0, stream>>>(
            x, (const float4*)Pc, Qc, pk, x3, W, bias, out);
    } else if (ws_size >= pk_bytes) {
        float4* pk = (float4*)d_ws;
        prep_pack8_kernel<<<(n + 255) / 256, 256, 0, stream>>>(Pc, Qc, W, pk, n);
        kan_kernel<1><<<grid, 256, 0, stream>>>(
            x, (const float4*)Pc, Qc, pk, nullptr, W, bias, out);
    } else {
        kan_kernel<0><<<grid, 256, 0, stream>>>(
            x, (const float4*)Pc, Qc, nullptr, nullptr, W, bias, out);
    }
}

// Round 10
// 191.110 us; speedup vs baseline: 4.4732x; 4.4732x over previous
//
#include <hip/hip_runtime.h>

constexpr int IN_F  = 256;
constexpr int OUT_F = 512;
constexpr int BATCH = 2048;

// pack[(o,i)] = {p0,p1,p2,p3 | q1,q2,q3,w} : one aligned 32B record; two
// adjacent i-records form a 64B-aligned group -> s_load_dwordx16.
__global__ __launch_bounds__(256) void prep_pack8_kernel(
    const float* __restrict__ p, const float* __restrict__ q,
    const float* __restrict__ w, float4* __restrict__ pk, int n) {
    int t = blockIdx.x * 256 + threadIdx.x;
    if (t < n) {
        pk[2 * t]     = make_float4(p[4 * t], p[4 * t + 1], p[4 * t + 2], p[4 * t + 3]);
        pk[2 * t + 1] = make_float4(q[3 * t], q[3 * t + 1], q[3 * t + 2], w[t]);
    }
}

// x3[b,i] = RN(x^3) via f64, once per (b,i).
__global__ __launch_bounds__(256) void prep_x3_kernel(
    const float* __restrict__ x, float* __restrict__ x3, int n) {
    int t = blockIdx.x * 256 + threadIdx.x;
    if (t < n) {
        const double xd = (double)x[t];
        x3[t] = (float)(xd * xd * xd);   // RN(x^3) == powf(x,3)
    }
}

// R10: R6 structure (s_load coefficient broadcast -- the only pipe that
// works; R7 LDS-staging, R8 unroll-2, R9 VMEM-broadcast all regressed)
// re-tiled to cut SMEM pressure: each lane owns TWO batches (b, b+64),
// block = 128 b x 4 o, waves split i. Each 64B coefficient group
// (s_load_dwordx16, 2 i-records) feeds 2x2 = 4 elements -> 4x fewer SMEM
// ops, 2x fewer SMEM bytes per element than R6. Grid stays 2048 blocks.
//
// NUMERICS (bit-exact vs np reference -- DO NOT REORDER, verified R3-R9,
// absmax 768 vs threshold 5.7e5). Per-(b,o) FP sequence identical to R6:
//   x^2 = RN(x*x); x^3 = RN(x^3) via f64 table; S = fmaf chain ascending p
//   starting from RN(c1*x); Q' = (1+S)+1e-6 as two separate adds; division
//   via rcp (relative-error-only); W-fma interleaved per element; i
//   ascending within wave; wave partials summed in order 0,1,2,3.
__global__ __launch_bounds__(256, 8) void kan2_kernel(
    const float*  __restrict__ x,
    const float4* __restrict__ PK,    // (O, I) 2x float4 records
    const float*  __restrict__ X3,    // (B, I) RN(x^3) table
    const float*  __restrict__ bias,  // (O)
    float* __restrict__ out)          // (B, O)
{
#pragma clang fp contract(off)       // protect the explicit add sequence
    const int lane  = threadIdx.x & 63;
    const int wave  = __builtin_amdgcn_readfirstlane(threadIdx.x >> 6);
    const int bA    = blockIdx.x * 128 + lane;      // batch A
    const int o0    = blockIdx.y * 4;
    const int ibase = wave * 64;                     // this wave's i-slice

    float accA[4] = {0.f, 0.f, 0.f, 0.f};
    float accB[4] = {0.f, 0.f, 0.f, 0.f};
    const float* xrowA  = x  + (size_t)bA * IN_F + ibase;
    const float* xrowB  = xrowA + (size_t)64 * IN_F;
    const float* x3rowA = X3 + (size_t)bA * IN_F + ibase;
    const float* x3rowB = x3rowA + (size_t)64 * IN_F;

    for (int ic = 0; ic < 64; ic += 4) {
        const float4 xqA  = *reinterpret_cast<const float4*>(xrowA + ic);
        const float4 x3qA = *reinterpret_cast<const float4*>(x3rowA + ic);
        const float4 xqB  = *reinterpret_cast<const float4*>(xrowB + ic);
        const float4 x3qB = *reinterpret_cast<const float4*>(x3rowB + ic);
        float x1A[4] = {xqA.x, xqA.y, xqA.z, xqA.w};
        float x3A[4] = {x3qA.x, x3qA.y, x3qA.z, x3qA.w};
        float x1B[4] = {xqB.x, xqB.y, xqB.z, xqB.w};
        float x3B[4] = {x3qB.x, x3qB.y, x3qB.z, x3qB.w};
        float x2A[4], x2B[4];
#pragma unroll
        for (int j = 0; j < 4; ++j) {
            x2A[j] = x1A[j] * x1A[j];               // RN(x^2)
            x2B[j] = x1B[j] * x1B[j];
        }
        const int rowi = ibase + ic;
#pragma unroll
        for (int oo = 0; oo < 4; ++oo) {
            // float4 index of record (o0+oo, rowi); 64B-aligned groups of 4.
            const size_t base = 2 * ((size_t)(o0 + oo) * IN_F + rowi);
#pragma unroll
            for (int jp = 0; jp < 2; ++jp) {        // two i-pairs
                const float4* rec = PK + base + 4 * jp;   // 64B uniform load
                const float4 r0 = rec[0];   // P coeffs, i = rowi+2*jp
                const float4 r1 = rec[1];   // Q coeffs + w
                const float4 r2 = rec[2];   // P coeffs, i+1
                const float4 r3 = rec[3];   // Q coeffs + w
#pragma unroll
                for (int h = 0; h < 2; ++h) {
                    const int j = 2 * jp + h;       // i ascending
                    const float4 cp = h ? r2 : r0;
                    const float4 cq = h ? r3 : r1;
                    // ---- batch A ----
                    {
                        float t = cq.x * x1A[j];
                        t = fmaf(cq.y, x2A[j], t);
                        t = fmaf(cq.z, x3A[j], t);
                        float Qv = 1.0f + t;        // Sterbenz-exact
                        float Qp = Qv + 1e-6f;
                        float s = fmaf(cp.y, x1A[j], cp.x);
                        s = fmaf(cp.z, x2A[j], s);
                        s = fmaf(cp.w, x3A[j], s);
                        const float r = __builtin_amdgcn_rcpf(Qp);
                        accA[oo] = fmaf(s, r, accA[oo]);
                        accA[oo] = fmaf(cq.w, x1A[j], accA[oo]);
                    }
                    // ---- batch B ----
                    {
                        float t = cq.x * x1B[j];
                        t = fmaf(cq.y, x2B[j], t);
                        t = fmaf(cq.z, x3B[j], t);
                        float Qv = 1.0f + t;
                        float Qp = Qv + 1e-6f;
                        float s = fmaf(cp.y, x1B[j], cp.x);
                        s = fmaf(cp.z, x2B[j], s);
                        s = fmaf(cp.w, x3B[j], s);
                        const float r = __builtin_amdgcn_rcpf(Qp);
                        accB[oo] = fmaf(s, r, accB[oo]);
                        accB[oo] = fmaf(cq.w, x1B[j], accB[oo]);
                    }
                }
            }
        }
    }

    // ---- cross-wave reduction: red[wave][lane][9-pad] ----
    __shared__ float red[4 * 64 * 9];
    {
        float* dst = &red[(wave * 64 + lane) * 9];
#pragma unroll
        for (int v = 0; v < 4; ++v) dst[v] = accA[v];
#pragma unroll
        for (int v = 0; v < 4; ++v) dst[4 + v] = accB[v];
    }
    __syncthreads();

#pragma unroll
    for (int k = 0; k < 2; ++k) {
        const int f  = threadIdx.x + k * 256;       // 0..511
        const int bb = f >> 2, o = f & 3;           // bb 0..127, o 0..3
        const int e  = (bb & 63) * 9 + (bb >> 6) * 4 + o;
        float s = red[e] + red[576 + e];            // wave order 0,1,2,3
        s = s + red[1152 + e];
        s = s + red[1728 + e];
        s = s + bias[o0 + o];
        out[(size_t)(blockIdx.x * 128 + bb) * OUT_F + o0 + o] = s;
    }
}

// R6 fallback (packed s_load / raw arrays) -- only used if ws too small.
template <int MODE>
__global__ __launch_bounds__(256, 8) void kan_kernel(
    const float*  __restrict__ x,
    const float4* __restrict__ Pc, const float* __restrict__ Qc,
    const float4* __restrict__ PK, const float* __restrict__ W,
    const float* __restrict__ bias, float* __restrict__ out)
{
#pragma clang fp contract(off)
    const int lane  = threadIdx.x & 63;
    const int wave  = __builtin_amdgcn_readfirstlane(threadIdx.x >> 6);
    const int b     = blockIdx.x * 64 + lane;
    const int o0    = blockIdx.y * 8;
    const int ibase = wave * 64;

    float acc[8] = {0.f, 0.f, 0.f, 0.f, 0.f, 0.f, 0.f, 0.f};
    const float* xrow = x + (size_t)b * IN_F + ibase;

    for (int ic = 0; ic < 64; ic += 4) {
        const float4 xq = *reinterpret_cast<const float4*>(xrow + ic);
        float x1[4] = {xq.x, xq.y, xq.z, xq.w};
        float x2[4], x3v[4];
#pragma unroll
        for (int j = 0; j < 4; ++j) {
            x2[j] = x1[j] * x1[j];
            const double xd = (double)x1[j];
            x3v[j] = (float)(xd * xd * xd);
        }
        const int rowi = ibase + ic;
#pragma unroll
        for (int oo = 0; oo < 8; ++oo) {
            const int rowbase = (o0 + oo) * IN_F + rowi;
#pragma unroll
            for (int j = 0; j < 4; ++j) {
                float p0, p1, p2, p3, q1, q2, q3, wv;
                if (MODE == 1) {
                    const float4 pa = PK[2 * (size_t)(rowbase + j)];
                    const float4 pb = PK[2 * (size_t)(rowbase + j) + 1];
                    p0 = pa.x; p1 = pa.y; p2 = pa.z; p3 = pa.w;
                    q1 = pb.x; q2 = pb.y; q3 = pb.z; wv = pb.w;
                } else {
                    const float4 pc = Pc[rowbase + j];
                    const float* qp = Qc + (size_t)(rowbase + j) * 3;
                    p0 = pc.x; p1 = pc.y; p2 = pc.z; p3 = pc.w;
                    q1 = qp[0]; q2 = qp[1]; q3 = qp[2];
                    wv = W[rowbase + j];
                }
                float t = q1 * x1[j];
                t = fmaf(q2, x2[j], t);
                t = fmaf(q3, x3v[j], t);
                float Qv = 1.0f + t;
                float Qp = Qv + 1e-6f;
                float s = fmaf(p1, x1[j], p0);
                s = fmaf(p2, x2[j], s);
                s = fmaf(p3, x3v[j], s);
                const float r = __builtin_amdgcn_rcpf(Qp);
                acc[oo] = fmaf(s, r, acc[oo]);
                acc[oo] = fmaf(wv, x1[j], acc[oo]);
            }
        }
    }

    __shared__ float red[4 * 64 * 9];
    {
        float* dst = &red[(wave * 64 + lane) * 9];
#pragma unroll
        for (int v = 0; v < 8; ++v) dst[v] = acc[v];
    }
    __syncthreads();
#pragma unroll
    for (int k = 0; k < 2; ++k) {
        const int idx = threadIdx.x + k * 256;
        const int bb = idx >> 3, o = idx & 7;
        const int e = bb * 9 + o;
        float s = red[e] + red[576 + e];
        s = s + red[1152 + e];
        s = s + red[1728 + e];
        s = s + bias[o0 + o];
        out[(size_t)(blockIdx.x * 64 + bb) * OUT_F + o0 + o] = s;
    }
}

extern "C" void kernel_launch(void* const* d_in, const int* in_sizes, int n_in,
                              void* d_out, int out_size, void* d_ws, size_t ws_size,
                              hipStream_t stream) {
    const float* x    = (const float*)d_in[0];
    const float* Pc   = (const float*)d_in[1];
    const float* Qc   = (const float*)d_in[2];
    const float* W    = (const float*)d_in[3];
    const float* bias = (const float*)d_in[4];
    float* out = (float*)d_out;

    const int n  = OUT_F * IN_F;          // 131072 (o,i) records
    const int nx = BATCH * IN_F;          // 524288 (b,i) x-powers
    const size_t pk_bytes = (size_t)n * 32;

    if (ws_size >= pk_bytes + (size_t)nx * sizeof(float)) {
        float4* pk = (float4*)d_ws;
        float*  x3 = (float*)((char*)d_ws + pk_bytes);
        prep_pack8_kernel<<<(n + 255) / 256, 256, 0, stream>>>(Pc, Qc, W, pk, n);
        prep_x3_kernel<<<(nx + 255) / 256, 256, 0, stream>>>(x, x3, nx);
        dim3 grid(BATCH / 128, OUT_F / 4);   // 2048 blocks = 8/CU
        kan2_kernel<<<grid, 256, 0, stream>>>(x, pk, x3, bias, out);
    } else if (ws_size >= pk_bytes) {
        float4* pk = (float4*)d_ws;
        prep_pack8_kernel<<<(n + 255) / 256, 256, 0, stream>>>(Pc, Qc, W, pk, n);
        dim3 grid(BATCH / 64, OUT_F / 8);
        kan_kernel<1><<<grid, 256, 0, stream>>>(
            x, (const float4*)Pc, Qc, pk, W, bias, out);
    } else {
        dim3 grid(BATCH / 64, OUT_F / 8);
        kan_kernel<0><<<grid, 256, 0, stream>>>(
            x, (const float4*)Pc, Qc, nullptr, W, bias, out);
    }
}

// Round 11
// 177.254 us; speedup vs baseline: 4.8229x; 1.0782x over previous
//
#include <hip/hip_runtime.h>

constexpr int IN_F  = 256;
constexpr int OUT_F = 512;
constexpr int BATCH = 2048;

// pack[(o,i)] = {p0,p1,p2,p3 | q1,q2,q3,w} : one aligned 32B record.
__global__ __launch_bounds__(256) void prep_pack8_kernel(
    const float* __restrict__ p, const float* __restrict__ q,
    const float* __restrict__ w, float4* __restrict__ pk, int n) {
    int t = blockIdx.x * 256 + threadIdx.x;
    if (t < n) {
        pk[2 * t]     = make_float4(p[4 * t], p[4 * t + 1], p[4 * t + 2], p[4 * t + 3]);
        pk[2 * t + 1] = make_float4(q[3 * t], q[3 * t + 1], q[3 * t + 2], w[t]);
    }
}

// x3[b,i] = RN(x^3) via f64, once per (b,i).
__global__ __launch_bounds__(256) void prep_x3_kernel(
    const float* __restrict__ x, float* __restrict__ x3, int n) {
    int t = blockIdx.x * 256 + threadIdx.x;
    if (t < n) {
        const double xd = (double)x[t];
        x3[t] = (float)(xd * xd * xd);   // RN(x^3) == powf(x,3)
    }
}

// R11: batch-pair tiling with R6's PROVEN load shape. Block = 128 b x 4 o;
// waves split i; lane owns batches (b, b+64). One s_load_dwordx8 per (o,i)
// record (32B -- the codegen R6 handled with zero spill) now feeds TWO
// elements -> SMEM ops and bytes per element halved vs R6.
// History: R7 LDS-staging (VGPR spill), R8 unroll-2 (sched regression),
// R9 VMEM-broadcast (VGPR spill), R10 x16-groups (SGPR spill) all lost to
// R6's 108us; this keeps R6's register/SGPR budgets intact.
//
// NUMERICS (bit-exact vs np reference -- DO NOT REORDER, verified R3-R10,
// absmax 768 vs threshold 5.7e5). Per-(b,o) FP sequence identical to R6:
//   x^2 = RN(x*x); x^3 = RN(x^3) via f64 table; S = fmaf chain ascending p
//   starting from RN(c1*x); Q' = (1+S)+1e-6 as two separate adds; division
//   via rcp (relative-error-only); W-fma interleaved per element; i
//   ascending within wave; wave partials summed in order 0,1,2,3.
__global__ __launch_bounds__(256, 8) void kan2_kernel(
    const float*  __restrict__ x,
    const float4* __restrict__ PK,    // (O, I) 2x float4 records
    const float*  __restrict__ X3,    // (B, I) RN(x^3) table
    const float*  __restrict__ bias,  // (O)
    float* __restrict__ out)          // (B, O)
{
#pragma clang fp contract(off)       // protect the explicit add sequence
    const int lane  = threadIdx.x & 63;
    const int wave  = __builtin_amdgcn_readfirstlane(threadIdx.x >> 6);
    const int bA    = blockIdx.x * 128 + lane;      // batch A
    const int o0    = blockIdx.y * 4;
    const int ibase = wave * 64;                     // this wave's i-slice

    float accA[4] = {0.f, 0.f, 0.f, 0.f};
    float accB[4] = {0.f, 0.f, 0.f, 0.f};
    const float* xrowA  = x  + (size_t)bA * IN_F + ibase;
    const float* xrowB  = xrowA + (size_t)64 * IN_F;
    const float* x3rowA = X3 + (size_t)bA * IN_F + ibase;
    const float* x3rowB = x3rowA + (size_t)64 * IN_F;

    for (int ic = 0; ic < 64; ic += 4) {
        const float4 xqA  = *reinterpret_cast<const float4*>(xrowA + ic);
        const float4 x3qA = *reinterpret_cast<const float4*>(x3rowA + ic);
        const float4 xqB  = *reinterpret_cast<const float4*>(xrowB + ic);
        const float4 x3qB = *reinterpret_cast<const float4*>(x3rowB + ic);
        float x1A[4] = {xqA.x, xqA.y, xqA.z, xqA.w};
        float x3A[4] = {x3qA.x, x3qA.y, x3qA.z, x3qA.w};
        float x1B[4] = {xqB.x, xqB.y, xqB.z, xqB.w};
        float x3B[4] = {x3qB.x, x3qB.y, x3qB.z, x3qB.w};
        float x2A[4], x2B[4];
#pragma unroll
        for (int j = 0; j < 4; ++j) {
            x2A[j] = x1A[j] * x1A[j];               // RN(x^2)
            x2B[j] = x1B[j] * x1B[j];
        }
        const int rowi = ibase + ic;
#pragma unroll
        for (int oo = 0; oo < 4; ++oo) {
            const int rowbase = (o0 + oo) * IN_F + rowi;
#pragma unroll
            for (int j = 0; j < 4; ++j) {          // R6-shape 32B records
                const float4 cp = PK[2 * (size_t)(rowbase + j)];
                const float4 cq = PK[2 * (size_t)(rowbase + j) + 1];
                // ---- batch A ----
                {
                    float t = cq.x * x1A[j];        // == fma(q1,x1,0)
                    t = fmaf(cq.y, x2A[j], t);
                    t = fmaf(cq.z, x3A[j], t);
                    float Qv = 1.0f + t;            // Sterbenz-exact
                    float Qp = Qv + 1e-6f;
                    float s = fmaf(cp.y, x1A[j], cp.x);
                    s = fmaf(cp.z, x2A[j], s);
                    s = fmaf(cp.w, x3A[j], s);
                    const float r = __builtin_amdgcn_rcpf(Qp);
                    accA[oo] = fmaf(s, r, accA[oo]);
                    accA[oo] = fmaf(cq.w, x1A[j], accA[oo]);
                }
                // ---- batch B ----
                {
                    float t = cq.x * x1B[j];
                    t = fmaf(cq.y, x2B[j], t);
                    t = fmaf(cq.z, x3B[j], t);
                    float Qv = 1.0f + t;
                    float Qp = Qv + 1e-6f;
                    float s = fmaf(cp.y, x1B[j], cp.x);
                    s = fmaf(cp.z, x2B[j], s);
                    s = fmaf(cp.w, x3B[j], s);
                    const float r = __builtin_amdgcn_rcpf(Qp);
                    accB[oo] = fmaf(s, r, accB[oo]);
                    accB[oo] = fmaf(cq.w, x1B[j], accB[oo]);
                }
            }
        }
    }

    // ---- cross-wave reduction: red[wave][lane][9-pad] (verified in R10) ----
    __shared__ float red[4 * 64 * 9];
    {
        float* dst = &red[(wave * 64 + lane) * 9];
#pragma unroll
        for (int v = 0; v < 4; ++v) dst[v] = accA[v];
#pragma unroll
        for (int v = 0; v < 4; ++v) dst[4 + v] = accB[v];
    }
    __syncthreads();

#pragma unroll
    for (int k = 0; k < 2; ++k) {
        const int f  = threadIdx.x + k * 256;       // 0..511
        const int bb = f >> 2, o = f & 3;           // bb 0..127, o 0..3
        const int e  = (bb & 63) * 9 + (bb >> 6) * 4 + o;
        float s = red[e] + red[576 + e];            // wave order 0,1,2,3
        s = s + red[1152 + e];
        s = s + red[1728 + e];
        s = s + bias[o0 + o];
        out[(size_t)(blockIdx.x * 128 + bb) * OUT_F + o0 + o] = s;
    }
}

// R6 fallback (packed s_load / raw arrays) -- only used if ws too small.
template <int MODE>
__global__ __launch_bounds__(256, 8) void kan_kernel(
    const float*  __restrict__ x,
    const float4* __restrict__ Pc, const float* __restrict__ Qc,
    const float4* __restrict__ PK, const float* __restrict__ W,
    const float* __restrict__ bias, float* __restrict__ out)
{
#pragma clang fp contract(off)
    const int lane  = threadIdx.x & 63;
    const int wave  = __builtin_amdgcn_readfirstlane(threadIdx.x >> 6);
    const int b     = blockIdx.x * 64 + lane;
    const int o0    = blockIdx.y * 8;
    const int ibase = wave * 64;

    float acc[8] = {0.f, 0.f, 0.f, 0.f, 0.f, 0.f, 0.f, 0.f};
    const float* xrow = x + (size_t)b * IN_F + ibase;

    for (int ic = 0; ic < 64; ic += 4) {
        const float4 xq = *reinterpret_cast<const float4*>(xrow + ic);
        float x1[4] = {xq.x, xq.y, xq.z, xq.w};
        float x2[4], x3v[4];
#pragma unroll
        for (int j = 0; j < 4; ++j) {
            x2[j] = x1[j] * x1[j];
            const double xd = (double)x1[j];
            x3v[j] = (float)(xd * xd * xd);
        }
        const int rowi = ibase + ic;
#pragma unroll
        for (int oo = 0; oo < 8; ++oo) {
            const int rowbase = (o0 + oo) * IN_F + rowi;
#pragma unroll
            for (int j = 0; j < 4; ++j) {
                float p0, p1, p2, p3, q1, q2, q3, wv;
                if (MODE == 1) {
                    const float4 pa = PK[2 * (size_t)(rowbase + j)];
                    const float4 pb = PK[2 * (size_t)(rowbase + j) + 1];
                    p0 = pa.x; p1 = pa.y; p2 = pa.z; p3 = pa.w;
                    q1 = pb.x; q2 = pb.y; q3 = pb.z; wv = pb.w;
                } else {
                    const float4 pc = Pc[rowbase + j];
                    const float* qp = Qc + (size_t)(rowbase + j) * 3;
                    p0 = pc.x; p1 = pc.y; p2 = pc.z; p3 = pc.w;
                    q1 = qp[0]; q2 = qp[1]; q3 = qp[2];
                    wv = W[rowbase + j];
                }
                float t = q1 * x1[j];
                t = fmaf(q2, x2[j], t);
                t = fmaf(q3, x3v[j], t);
                float Qv = 1.0f + t;
                float Qp = Qv + 1e-6f;
                float s = fmaf(p1, x1[j], p0);
                s = fmaf(p2, x2[j], s);
                s = fmaf(p3, x3v[j], s);
                const float r = __builtin_amdgcn_rcpf(Qp);
                acc[oo] = fmaf(s, r, acc[oo]);
                acc[oo] = fmaf(wv, x1[j], acc[oo]);
            }
        }
    }

    __shared__ float red[4 * 64 * 9];
    {
        float* dst = &red[(wave * 64 + lane) * 9];
#pragma unroll
        for (int v = 0; v < 8; ++v) dst[v] = acc[v];
    }
    __syncthreads();
#pragma unroll
    for (int k = 0; k < 2; ++k) {
        const int idx = threadIdx.x + k * 256;
        const int bb = idx >> 3, o = idx & 7;
        const int e = bb * 9 + o;
        float s = red[e] + red[576 + e];
        s = s + red[1152 + e];
        s = s + red[1728 + e];
        s = s + bias[o0 + o];
        out[(size_t)(blockIdx.x * 64 + bb) * OUT_F + o0 + o] = s;
    }
}

extern "C" void kernel_launch(void* const* d_in, const int* in_sizes, int n_in,
                              void* d_out, int out_size, void* d_ws, size_t ws_size,
                              hipStream_t stream) {
    const float* x    = (const float*)d_in[0];
    const float* Pc   = (const float*)d_in[1];
    const float* Qc   = (const float*)d_in[2];
    const float* W    = (const float*)d_in[3];
    const float* bias = (const float*)d_in[4];
    float* out = (float*)d_out;

    const int n  = OUT_F * IN_F;          // 131072 (o,i) records
    const int nx = BATCH * IN_F;          // 524288 (b,i) x-powers
    const size_t pk_bytes = (size_t)n * 32;

    if (ws_size >= pk_bytes + (size_t)nx * sizeof(float)) {
        float4* pk = (float4*)d_ws;
        float*  x3 = (float*)((char*)d_ws + pk_bytes);
        prep_pack8_kernel<<<(n + 255) / 256, 256, 0, stream>>>(Pc, Qc, W, pk, n);
        prep_x3_kernel<<<(nx + 255) / 256, 256, 0, stream>>>(x, x3, nx);
        dim3 grid(BATCH / 128, OUT_F / 4);   // 2048 blocks = 8/CU
        kan2_kernel<<<grid, 256, 0, stream>>>(x, pk, x3, bias, out);
    } else if (ws_size >= pk_bytes) {
        float4* pk = (float4*)d_ws;
        prep_pack8_kernel<<<(n + 255) / 256, 256, 0, stream>>>(Pc, Qc, W, pk, n);
        dim3 grid(BATCH / 64, OUT_F / 8);
        kan_kernel<1><<<grid, 256, 0, stream>>>(
            x, (const float4*)Pc, Qc, pk, W, bias, out);
    } else {
        dim3 grid(BATCH / 64, OUT_F / 8);
        kan_kernel<0><<<grid, 256, 0, stream>>>(
            x, (const float4*)Pc, Qc, nullptr, W, bias, out);
    }
}

// Round 12
// 172.585 us; speedup vs baseline: 4.9534x; 1.0271x over previous
//
#include <hip/hip_runtime.h>

constexpr int IN_F  = 256;
constexpr int OUT_F = 512;
constexpr int BATCH = 2048;

// pack[(o,i)] = {p0,p1,p2,p3 | q1,q2,q3,w} : one aligned 32B record.
__global__ __launch_bounds__(256) void prep_pack8_kernel(
    const float* __restrict__ p, const float* __restrict__ q,
    const float* __restrict__ w, float4* __restrict__ pk, int n) {
    int t = blockIdx.x * 256 + threadIdx.x;
    if (t < n) {
        pk[2 * t]     = make_float4(p[4 * t], p[4 * t + 1], p[4 * t + 2], p[4 * t + 3]);
        pk[2 * t + 1] = make_float4(q[3 * t], q[3 * t + 1], q[3 * t + 2], w[t]);
    }
}

// x3[b,i] = RN(x^3) via f64, once per (b,i).
__global__ __launch_bounds__(256) void prep_x3_kernel(
    const float* __restrict__ x, float* __restrict__ x3, int n) {
    int t = blockIdx.x * 256 + threadIdx.x;
    if (t < n) {
        const double xd = (double)x[t];
        x3[t] = (float)(xd * xd * xd);   // RN(x^3) == powf(x,3)
    }
}

// R12: EXACT R6 compute shape (same tiling: 64 b lanes x 8 o, waves split i;
// same 32 unrolled bodies per 4-i chunk; same acc[8]+x-state register
// profile; same grid 2048 blocks = 8/CU; same padded reduction) with ONE
// delta: coefficient delivery s_load -> global_load_lds staging + broadcast
// ds_read_b128. gload_lds has zero VGPR cost (the R7 reg-staging failure
// mode cannot recur); the 8KB double-buffer overlays the 9KB reduction
// arena so LDS stays 9216B. One __syncthreads per chunk drains vmcnt
// (compiler semantics) -> staged tile guaranteed visible.
// History: R7 LDS reg-staging (VGPR spill), R8 unroll-2, R9 VMEM broadcast
// (VGPR spill), R10 x16 s_load groups (SGPR spill), R11 batch-pair (spill)
// all lost to R6's 108us. This is the minimal-delta pipe swap.
//
// NUMERICS (bit-exact vs np reference -- DO NOT REORDER, verified R3-R11,
// absmax 768 vs threshold 5.7e5). Per-(b,o) FP sequence identical to R6:
//   x^2 = RN(x*x); x^3 = RN(x^3) via f64 table; S = fmaf chain ascending p
//   starting from RN(c1*x); Q' = (1+S)+1e-6 as two separate adds; division
//   via rcp (relative-error-only); W-fma interleaved per element; i
//   ascending within wave; wave partials summed in order 0,1,2,3.
__global__ __launch_bounds__(256, 8) void kan3_kernel(
    const float*  __restrict__ x,
    const float4* __restrict__ PK,    // (O, I) 2x float4 records
    const float*  __restrict__ X3,    // (B, I) RN(x^3) table
    const float*  __restrict__ bias,  // (O)
    float* __restrict__ out)          // (B, O)
{
#pragma clang fp contract(off)       // protect the explicit add sequence
    const int lane  = threadIdx.x & 63;
    const int wave  = __builtin_amdgcn_readfirstlane(threadIdx.x >> 6);
    const int b     = blockIdx.x * 64 + lane;
    const int o0    = blockIdx.y * 8;
    const int ibase = wave * 64;      // this wave's i-slice

    // Arena: [0..511] float4 = 2 x 4KB coefficient tiles (double buffer);
    // whole 9216B overlaid by the reduction at the end.
    __shared__ float4 arena4[576];    // 9216 B

    // ---- staging geometry (one global_load_lds per wave per chunk) ----
    // Chunk c stages, for ALL waves, records (o0+oo, i) with
    // i = 64*wv + 4*c + jj  (wv = consuming wave, jj = 0..3).
    // Tile entry index = oo*16 + wv*4 + jj  (128 records = 4KB).
    // Call for wave w covers entries [w*32, w*32+32): lane l -> 16B piece
    //   sub = l>>1, half = l&1; oo = 2w + (sub>>4); iw = sub&15;
    //   wv = iw>>2; jj = iw&3.
    const int sub  = lane >> 1;
    const int half = lane & 1;
    const int s_oo = 2 * wave + (sub >> 4);
    const int s_wv = (sub & 15) >> 2;
    const int s_jj = sub & 3;
    const char* src = (const char*)PK
        + (((size_t)(o0 + s_oo) * IN_F + 64 * s_wv + s_jj) * 32) + half * 16;

    float acc[8] = {0.f, 0.f, 0.f, 0.f, 0.f, 0.f, 0.f, 0.f};
    const float* xrow  = x  + (size_t)b * IN_F + ibase;
    const float* x3row = X3 + (size_t)b * IN_F + ibase;

    // prologue: stage chunk 0 into buffer 0
    {
        float4* dst = &arena4[0 * 256 + wave * 64];   // + lane*16B implicit
        __builtin_amdgcn_global_load_lds(
            (const __attribute__((address_space(1))) void*)src,
            (__attribute__((address_space(3))) void*)dst, 16, 0, 0);
    }
    __syncthreads();

    int par = 0;
    for (int c = 0; c < 16; ++c) {
        if (c < 15) {                 // stage chunk c+1 into the other half
            const char* s = src + (size_t)(c + 1) * 128;   // 4 records = 128B
            float4* dst = &arena4[(par ^ 1) * 256 + wave * 64];
            __builtin_amdgcn_global_load_lds(
                (const __attribute__((address_space(1))) void*)s,
                (__attribute__((address_space(3))) void*)dst, 16, 0, 0);
        }
        // ---- compute chunk c : i = ibase + 4c + j, j = 0..3 ----
        const float4 xq  = *reinterpret_cast<const float4*>(xrow  + 4 * c);
        const float4 x3q = *reinterpret_cast<const float4*>(x3row + 4 * c);
        float x1[4]  = {xq.x, xq.y, xq.z, xq.w};
        float x3v[4] = {x3q.x, x3q.y, x3q.z, x3q.w};
        float x2[4];
#pragma unroll
        for (int j = 0; j < 4; ++j) x2[j] = x1[j] * x1[j];   // RN(x^2)

        const float4* tile = &arena4[par * 256];
#pragma unroll
        for (int oo = 0; oo < 8; ++oo) {
#pragma unroll
            for (int j = 0; j < 4; ++j) {
                const int ent = oo * 16 + wave * 4 + j;      // broadcast read
                const float4 cp = tile[2 * ent];
                const float4 cq = tile[2 * ent + 1];
                // ---- S_Q : einsum fmaf chain, accum starts at 0 ----
                float t = cq.x * x1[j];            // == fma(q1,x1,0)
                t = fmaf(cq.y, x2[j], t);
                t = fmaf(cq.z, x3v[j], t);
                float Qv = 1.0f + t;               // Sterbenz-exact near pole
                float Qp = Qv + 1e-6f;
                // ---- S_P : same einsum chain ----
                float s = fmaf(cp.y, x1[j], cp.x);
                s = fmaf(cp.z, x2[j], s);
                s = fmaf(cp.w, x3v[j], s);
                const float r = __builtin_amdgcn_rcpf(Qp);
                acc[oo] = fmaf(s, r, acc[oo]);       // rational term
                acc[oo] = fmaf(cq.w, x1[j], acc[oo]);// fused base matmul
            }
        }
        __syncthreads();              // drains vmcnt (stage done) + sync
        par ^= 1;
    }

    // ---- cross-wave reduction (overlays arena): red[wave][lane][9] ----
    float* red = (float*)arena4;
    {
        float* dst = &red[(wave * 64 + lane) * 9];
#pragma unroll
        for (int v = 0; v < 8; ++v) dst[v] = acc[v];
    }
    __syncthreads();

#pragma unroll
    for (int k = 0; k < 2; ++k) {
        const int idx = threadIdx.x + k * 256;     // idx = bb*8 + o
        const int bb = idx >> 3, o = idx & 7;
        const int e = bb * 9 + o;
        float s = red[e] + red[576 + e];           // wave order 0,1,2,3
        s = s + red[1152 + e];
        s = s + red[1728 + e];
        s = s + bias[o0 + o];
        out[(size_t)(blockIdx.x * 64 + bb) * OUT_F + o0 + o] = s;
    }
}

// R6 fallback (packed s_load / raw arrays) -- only used if ws too small.
template <int MODE>
__global__ __launch_bounds__(256, 8) void kan_kernel(
    const float*  __restrict__ x,
    const float4* __restrict__ Pc, const float* __restrict__ Qc,
    const float4* __restrict__ PK, const float* __restrict__ W,
    const float* __restrict__ bias, float* __restrict__ out)
{
#pragma clang fp contract(off)
    const int lane  = threadIdx.x & 63;
    const int wave  = __builtin_amdgcn_readfirstlane(threadIdx.x >> 6);
    const int b     = blockIdx.x * 64 + lane;
    const int o0    = blockIdx.y * 8;
    const int ibase = wave * 64;

    float acc[8] = {0.f, 0.f, 0.f, 0.f, 0.f, 0.f, 0.f, 0.f};
    const float* xrow = x + (size_t)b * IN_F + ibase;

    for (int ic = 0; ic < 64; ic += 4) {
        const float4 xq = *reinterpret_cast<const float4*>(xrow + ic);
        float x1[4] = {xq.x, xq.y, xq.z, xq.w};
        float x2[4], x3v[4];
#pragma unroll
        for (int j = 0; j < 4; ++j) {
            x2[j] = x1[j] * x1[j];
            const double xd = (double)x1[j];
            x3v[j] = (float)(xd * xd * xd);
        }
        const int rowi = ibase + ic;
#pragma unroll
        for (int oo = 0; oo < 8; ++oo) {
            const int rowbase = (o0 + oo) * IN_F + rowi;
#pragma unroll
            for (int j = 0; j < 4; ++j) {
                float p0, p1, p2, p3, q1, q2, q3, wv;
                if (MODE == 1) {
                    const float4 pa = PK[2 * (size_t)(rowbase + j)];
                    const float4 pb = PK[2 * (size_t)(rowbase + j) + 1];
                    p0 = pa.x; p1 = pa.y; p2 = pa.z; p3 = pa.w;
                    q1 = pb.x; q2 = pb.y; q3 = pb.z; wv = pb.w;
                } else {
                    const float4 pc = Pc[rowbase + j];
                    const float* qp = Qc + (size_t)(rowbase + j) * 3;
                    p0 = pc.x; p1 = pc.y; p2 = pc.z; p3 = pc.w;
                    q1 = qp[0]; q2 = qp[1]; q3 = qp[2];
                    wv = W[rowbase + j];
                }
                float t = q1 * x1[j];
                t = fmaf(q2, x2[j], t);
                t = fmaf(q3, x3v[j], t);
                float Qv = 1.0f + t;
                float Qp = Qv + 1e-6f;
                float s = fmaf(p1, x1[j], p0);
                s = fmaf(p2, x2[j], s);
                s = fmaf(p3, x3v[j], s);
                const float r = __builtin_amdgcn_rcpf(Qp);
                acc[oo] = fmaf(s, r, acc[oo]);
                acc[oo] = fmaf(wv, x1[j], acc[oo]);
            }
        }
    }

    __shared__ float red[4 * 64 * 9];
    {
        float* dst = &red[(wave * 64 + lane) * 9];
#pragma unroll
        for (int v = 0; v < 8; ++v) dst[v] = acc[v];
    }
    __syncthreads();
#pragma unroll
    for (int k = 0; k < 2; ++k) {
        const int idx = threadIdx.x + k * 256;
        const int bb = idx >> 3, o = idx & 7;
        const int e = bb * 9 + o;
        float s = red[e] + red[576 + e];
        s = s + red[1152 + e];
        s = s + red[1728 + e];
        s = s + bias[o0 + o];
        out[(size_t)(blockIdx.x * 64 + bb) * OUT_F + o0 + o] = s;
    }
}

extern "C" void kernel_launch(void* const* d_in, const int* in_sizes, int n_in,
                              void* d_out, int out_size, void* d_ws, size_t ws_size,
                              hipStream_t stream) {
    const float* x    = (const float*)d_in[0];
    const float* Pc   = (const float*)d_in[1];
    const float* Qc   = (const float*)d_in[2];
    const float* W    = (const float*)d_in[3];
    const float* bias = (const float*)d_in[4];
    float* out = (float*)d_out;

    const int n  = OUT_F * IN_F;          // 131072 (o,i) records
    const int nx = BATCH * IN_F;          // 524288 (b,i) x-powers
    const size_t pk_bytes = (size_t)n * 32;
    dim3 grid(BATCH / 64, OUT_F / 8);     // 2048 blocks = 8/CU

    if (ws_size >= pk_bytes + (size_t)nx * sizeof(float)) {
        float4* pk = (float4*)d_ws;
        float*  x3 = (float*)((char*)d_ws + pk_bytes);
        prep_pack8_kernel<<<(n + 255) / 256, 256, 0, stream>>>(Pc, Qc, W, pk, n);
        prep_x3_kernel<<<(nx + 255) / 256, 256, 0, stream>>>(x, x3, nx);
        kan3_kernel<<<grid, 256, 0, stream>>>(x, pk, x3, bias, out);
    } else if (ws_size >= pk_bytes) {
        float4* pk = (float4*)d_ws;
        prep_pack8_kernel<<<(n + 255) / 256, 256, 0, stream>>>(Pc, Qc, W, pk, n);
        kan_kernel<1><<<grid, 256, 0, stream>>>(
            x, (const float4*)Pc, Qc, pk, W, bias, out);
    } else {
        kan_kernel<0><<<grid, 256, 0, stream>>>(
            x, (const float4*)Pc, Qc, nullptr, W, bias, out);
    }
}